// Round 4
// baseline (105.988 us; speedup 1.0000x reference)
//
#include <hip/hip_runtime.h>
#include <math.h>

namespace {

constexpr int kD = 1024;
constexpr int kL = 1024;
constexpr int kN = 16;
constexpr int kT = 512;   // threads per block; block = one (b,d)
constexpr int kJ = 8;     // n-states per thread (nh = t&1 selects half)
constexpr int kE = 4;     // l-steps per thread

__global__ __launch_bounds__(kT, 6)
void selscan(const float* __restrict__ u,
             const float* __restrict__ delta,
             const float* __restrict__ A,
             const float* __restrict__ Bm,
             const float* __restrict__ Cm,
             const float* __restrict__ Dv,
             const float* __restrict__ z,
             float* __restrict__ out)
{
    // per-wave scan summaries / carries: [wave][n]
    __shared__ __align__(16) float swa[8][16];
    __shared__ __align__(16) float swx[8][16];
    __shared__ __align__(16) float sci[8][16];

    const int bd   = blockIdx.x;
    const int b    = bd >> 10;           // kD = 1024
    const int d    = bd & (kD - 1);
    const int t    = threadIdx.x;
    const int lane = t & 63;
    const int wave = t >> 6;
    const int nh   = t & 1;              // which half of the 16 n
    const int n0   = nh << 3;
    const int l0   = (t >> 1) << 2;      // chunk base in l (chunk = t>>1)
    const size_t base = (size_t)bd * kL;

    const float LOG2E = 1.4426950408889634f;
    const float LN2   = 0.6931471805599453f;

    // ---- dt = softplus(delta), dtu = dt*u (float4, shared by lane pairs) ----
    float dt[kE], dtu[kE];
    {
        float4 dv = *(const float4*)(delta + base + l0);
        float4 uv = *(const float4*)(u + base + l0);
        float dd[kE] = {dv.x, dv.y, dv.z, dv.w};
        float uu[kE] = {uv.x, uv.y, uv.z, uv.w};
        #pragma unroll
        for (int s = 0; s < kE; ++s) {
            float x = dd[s];
            float e = __builtin_amdgcn_exp2f(-fabsf(x) * LOG2E);
            float sp = fmaxf(x, 0.f) + __builtin_amdgcn_logf(1.f + e) * LN2;
            dt[s]  = sp;
            dtu[s] = sp * uu[s];
        }
    }

    // ---- A row, pre-scaled by log2(e) for exp2 ----
    float cj[kJ];
    {
        float4 a0 = *(const float4*)(A + d * kN + n0);
        float4 a1 = *(const float4*)(A + d * kN + n0 + 4);
        cj[0]=a0.x*LOG2E; cj[1]=a0.y*LOG2E; cj[2]=a0.z*LOG2E; cj[3]=a0.w*LOG2E;
        cj[4]=a1.x*LOG2E; cj[5]=a1.y*LOG2E; cj[6]=a1.z*LOG2E; cj[7]=a1.w*LOG2E;
    }

    // ---- Phase 1: local scan; accumulate y_local and Q = P*C ----
    float Q[kJ][kE];
    float y[kE] = {0.f, 0.f, 0.f, 0.f};
    float a_s[kJ], x_s[kJ];
    const int rowbase = (b << 4) + n0;
    #pragma unroll
    for (int j = 0; j < kJ; ++j) {
        const float* Bp = Bm + (size_t)(rowbase + j) * kL + l0;
        const float* Cp = Cm + (size_t)(rowbase + j) * kL + l0;
        float4 b4 = *(const float4*)Bp;
        float4 c4 = *(const float4*)Cp;
        float Bv[kE] = {b4.x, b4.y, b4.z, b4.w};
        float Cv[kE] = {c4.x, c4.y, c4.z, c4.w};
        float x = 0.f, p = 1.f;
        #pragma unroll
        for (int s = 0; s < kE; ++s) {
            float e = __builtin_amdgcn_exp2f(dt[s] * cj[j]);
            x = fmaf(e, x, dtu[s] * Bv[s]);
            p *= e;
            Q[j][s] = p * Cv[s];
            y[s] = fmaf(x, Cv[s], y[s]);
        }
        a_s[j] = p;
        x_s[j] = x;
    }

    // ---- In-wave Hillis-Steele inclusive scan over 32 chunks (stride 2) ----
    #pragma unroll
    for (int dlt = 2; dlt <= 32; dlt <<= 1) {
        #pragma unroll
        for (int j = 0; j < kJ; ++j) {
            float ain = __shfl_up(a_s[j], dlt, 64);
            float xin = __shfl_up(x_s[j], dlt, 64);
            bool act = (lane >= dlt);
            x_s[j] = fmaf(a_s[j], act ? xin : 0.f, x_s[j]);
            a_s[j] *= act ? ain : 1.f;
        }
    }

    // ---- Wave summaries (last chunk's lane pair holds wave totals) ----
    if (lane >= 62) {
        *(float4*)&swa[wave][n0]     = make_float4(a_s[0], a_s[1], a_s[2], a_s[3]);
        *(float4*)&swa[wave][n0 + 4] = make_float4(a_s[4], a_s[5], a_s[6], a_s[7]);
        *(float4*)&swx[wave][n0]     = make_float4(x_s[0], x_s[1], x_s[2], x_s[3]);
        *(float4*)&swx[wave][n0 + 4] = make_float4(x_s[4], x_s[5], x_s[6], x_s[7]);
    }
    __syncthreads();

    // ---- Serial scan over 8 wave summaries, 16 lanes (one per n) ----
    if (t < kN) {
        float c = 0.f;
        #pragma unroll
        for (int w = 0; w < 8; ++w) {
            sci[w][t] = c;
            c = fmaf(swa[w][t], c, swx[w][t]);
        }
    }
    __syncthreads();

    // ---- Carry into this thread's chunk ----
    float4 w0 = *(const float4*)&sci[wave][n0];
    float4 w1 = *(const float4*)&sci[wave][n0 + 4];
    float wc[kJ] = {w0.x, w0.y, w0.z, w0.w, w1.x, w1.y, w1.z, w1.w};
    float carry[kJ];
    #pragma unroll
    for (int j = 0; j < kJ; ++j) {
        float av = __shfl_up(a_s[j], 2, 64);
        float xv = __shfl_up(x_s[j], 2, 64);
        float ea = (lane >= 2) ? av : 1.f;
        float ex = (lane >= 2) ? xv : 0.f;
        carry[j] = fmaf(ea, wc[j], ex);
    }

    // ---- Phase 2: y += carry_j * Q_j ----
    #pragma unroll
    for (int j = 0; j < kJ; ++j)
        #pragma unroll
        for (int s = 0; s < kE; ++s)
            y[s] = fmaf(carry[j], Q[j][s], y[s]);

    // ---- Reduce over the two n-halves (lane pairs) ----
    #pragma unroll
    for (int s = 0; s < kE; ++s)
        y[s] += __shfl_xor(y[s], 1, 64);

    // ---- Epilogue: thread writes l = 2t, 2t+1 (float2, fully coalesced) ----
    const float D_d = Dv[d];
    float y0 = nh ? y[2] : y[0];
    float y1 = nh ? y[3] : y[1];

    const int eo = 2 * t;
    float2 zv = *(const float2*)(z + base + eo);
    float2 uv = *(const float2*)(u + base + eo);
    float s0 = __builtin_amdgcn_rcpf(1.f + __builtin_amdgcn_exp2f(-zv.x * LOG2E));
    float s1 = __builtin_amdgcn_rcpf(1.f + __builtin_amdgcn_exp2f(-zv.y * LOG2E));
    float2 o;
    o.x = (y0 + uv.x * D_d) * zv.x * s0;
    o.y = (y1 + uv.y * D_d) * zv.y * s1;
    *(float2*)(out + base + eo) = o;
}

}  // namespace

extern "C" void kernel_launch(void* const* d_in, const int* in_sizes, int n_in,
                              void* d_out, int out_size, void* d_ws, size_t ws_size,
                              hipStream_t stream) {
    const float* u     = (const float*)d_in[0];
    const float* delta = (const float*)d_in[1];
    const float* A     = (const float*)d_in[2];
    const float* Bm    = (const float*)d_in[3];
    const float* Cm    = (const float*)d_in[4];
    const float* Dv    = (const float*)d_in[5];
    const float* z     = (const float*)d_in[6];
    float* out = (float*)d_out;

    dim3 grid(2 * kD);
    dim3 block(kT);
    hipLaunchKernelGGL(selscan, grid, block, 0, stream,
                       u, delta, A, Bm, Cm, Dv, z, out);
}

// Round 5
// 51.711 us; speedup vs baseline: 2.0496x; 2.0496x over previous
//
#include <hip/hip_runtime.h>
#include <math.h>

namespace {

constexpr int kD = 1024;
constexpr int kL = 1024;
constexpr int kN = 16;

// block = one (b,d): 1024 threads, each owns 4 l-steps x 4 n-states.
// lane = 4*chunk_in_wave + ng ; wave covers 64 consecutive l.
__global__ __launch_bounds__(1024, 2)
void selscan(const float* __restrict__ u,
             const float* __restrict__ delta,
             const float* __restrict__ A,
             const float* __restrict__ Bm,
             const float* __restrict__ Cm,
             const float* __restrict__ Dv,
             const float* __restrict__ z,
             float* __restrict__ out)
{
    __shared__ __align__(16) float swa[16][16];  // [wave][n] chunk-product a
    __shared__ __align__(16) float swx[16][16];  // [wave][n] chunk-scan x
    __shared__ __align__(16) float sci[16][16];  // [wave][n] carry into wave

    const int bd   = blockIdx.x;
    const int b    = bd >> 10;            // kD = 1024
    const int d    = bd & (kD - 1);
    const int t    = threadIdx.x;
    const int wave = t >> 6;
    const int lane = t & 63;
    const int ng   = lane & 3;            // n-group: states 4*ng .. 4*ng+3
    const int n0   = ng << 2;
    const int l0   = (t >> 2) << 2;       // this thread's chunk base in l
    const size_t base = (size_t)bd * kL;

    // ---- dt = softplus(delta), dtu = dt*u for the 4-step chunk ----
    float dt[4], dtu[4];
    {
        float4 dv = *(const float4*)(delta + base + l0);
        float4 uv = *(const float4*)(u + base + l0);
        float dd[4] = {dv.x, dv.y, dv.z, dv.w};
        float uu[4] = {uv.x, uv.y, uv.z, uv.w};
        #pragma unroll
        for (int s = 0; s < 4; ++s) {
            float x  = dd[s];
            float sp = fmaxf(x, 0.f) + __logf(1.f + __expf(-fabsf(x)));
            dt[s]  = sp;
            dtu[s] = sp * uu[s];
        }
    }

    // ---- A row (pre-scaled by log2e for exp2) ----
    const float LOG2E = 1.4426950408889634f;
    float cj[4];
    {
        float4 a4 = *(const float4*)(A + d * kN + n0);
        cj[0] = a4.x * LOG2E; cj[1] = a4.y * LOG2E;
        cj[2] = a4.z * LOG2E; cj[3] = a4.w * LOG2E;
    }

    // ---- Phase 1: local scan; accumulate y_local and Q = P*C ----
    float Q[4][4];
    float y[4] = {0.f, 0.f, 0.f, 0.f};
    float a_s[4], x_s[4];
    const int rowbase = (b << 4) + n0;
    #pragma unroll
    for (int j = 0; j < 4; ++j) {
        const float* Bp = Bm + (size_t)(rowbase + j) * kL + l0;
        const float* Cp = Cm + (size_t)(rowbase + j) * kL + l0;
        float4 b4 = *(const float4*)Bp;
        float4 c4 = *(const float4*)Cp;
        float Bv[4] = {b4.x, b4.y, b4.z, b4.w};
        float Cv[4] = {c4.x, c4.y, c4.z, c4.w};
        float x = 0.f, p = 1.f;
        #pragma unroll
        for (int s = 0; s < 4; ++s) {
            float e = __builtin_amdgcn_exp2f(dt[s] * cj[j]);
            x = fmaf(e, x, dtu[s] * Bv[s]);
            p *= e;
            Q[j][s] = p * Cv[s];
            y[s] = fmaf(x, Cv[s], y[s]);
        }
        a_s[j] = p;
        x_s[j] = x;
    }

    // ---- In-wave Hillis-Steele inclusive scan over 16 chunks (stride 4) ----
    #pragma unroll
    for (int dlt = 4; dlt <= 32; dlt <<= 1) {
        #pragma unroll
        for (int j = 0; j < 4; ++j) {
            float ain = __shfl_up(a_s[j], dlt, 64);
            float xin = __shfl_up(x_s[j], dlt, 64);
            bool act = (lane >= dlt);
            ain = act ? ain : 1.f;
            xin = act ? xin : 0.f;
            x_s[j] = fmaf(a_s[j], xin, x_s[j]);
            a_s[j] *= ain;
        }
    }

    // ---- Wave summaries (chunk 15 lanes hold wave-inclusive totals) ----
    if (lane >= 60) {
        *(float4*)&swa[wave][n0] = make_float4(a_s[0], a_s[1], a_s[2], a_s[3]);
        *(float4*)&swx[wave][n0] = make_float4(x_s[0], x_s[1], x_s[2], x_s[3]);
    }
    __syncthreads();

    // ---- Log-time scan of the 16 wave summaries (single wave) ----
    if (wave == 0) {
        int w = lane >> 2, q = lane & 3;           // lane covers (wave w, 4 n)
        float4 aa = *(const float4*)&swa[w][q << 2];
        float4 xx = *(const float4*)&swx[w][q << 2];
        float as[4] = {aa.x, aa.y, aa.z, aa.w};
        float xs[4] = {xx.x, xx.y, xx.z, xx.w};
        #pragma unroll
        for (int dlt = 4; dlt <= 32; dlt <<= 1) {
            #pragma unroll
            for (int j = 0; j < 4; ++j) {
                float ain = __shfl_up(as[j], dlt, 64);
                float xin = __shfl_up(xs[j], dlt, 64);
                bool act = (lane >= dlt);
                ain = act ? ain : 1.f;
                xin = act ? xin : 0.f;
                xs[j] = fmaf(as[j], xin, xs[j]);
                as[j] *= ain;
            }
        }
        // exclusive (carry INTO wave w) = inclusive through w-1
        float ex[4];
        #pragma unroll
        for (int j = 0; j < 4; ++j) {
            float xv = __shfl_up(xs[j], 4, 64);
            ex[j] = (lane >= 4) ? xv : 0.f;
        }
        *(float4*)&sci[w][q << 2] = make_float4(ex[0], ex[1], ex[2], ex[3]);
    }
    __syncthreads();

    // ---- Carry into this thread's chunk ----
    float4 wc4 = *(const float4*)&sci[wave][n0];
    float wc[4] = {wc4.x, wc4.y, wc4.z, wc4.w};
    float carry[4];
    #pragma unroll
    for (int j = 0; j < 4; ++j) {
        float av = __shfl_up(a_s[j], 4, 64);
        float xv = __shfl_up(x_s[j], 4, 64);
        float ea = (lane >= 4) ? av : 1.f;
        float ex = (lane >= 4) ? xv : 0.f;
        carry[j] = fmaf(ea, wc[j], ex);
    }

    // ---- Phase 2: y += carry_j * Q_j ----
    #pragma unroll
    for (int j = 0; j < 4; ++j)
        #pragma unroll
        for (int s = 0; s < 4; ++s)
            y[s] = fmaf(carry[j], Q[j][s], y[s]);

    // ---- Reduce over the 4 n-groups (lane bits 0-1) ----
    #pragma unroll
    for (int s = 0; s < 4; ++s) {
        y[s] += __shfl_xor(y[s], 1, 64);
        y[s] += __shfl_xor(y[s], 2, 64);
    }
    float yo = (ng == 0) ? y[0] : (ng == 1) ? y[1] : (ng == 2) ? y[2] : y[3];

    // ---- Epilogue: out[base+t] = (y + u*D) * silu(z)  (fully coalesced) ----
    const float D_d = Dv[d];
    float uo = u[base + t];
    float zo = z[base + t];
    float sig = __builtin_amdgcn_rcpf(1.f + __expf(-zo));
    out[base + t] = (yo + uo * D_d) * zo * sig;
}

}  // namespace

extern "C" void kernel_launch(void* const* d_in, const int* in_sizes, int n_in,
                              void* d_out, int out_size, void* d_ws, size_t ws_size,
                              hipStream_t stream) {
    const float* u     = (const float*)d_in[0];
    const float* delta = (const float*)d_in[1];
    const float* A     = (const float*)d_in[2];
    const float* Bm    = (const float*)d_in[3];
    const float* Cm    = (const float*)d_in[4];
    const float* Dv    = (const float*)d_in[5];
    const float* z     = (const float*)d_in[6];
    float* out = (float*)d_out;

    dim3 grid(2 * kD);
    dim3 block(1024);
    hipLaunchKernelGGL(selscan, grid, block, 0, stream,
                       u, delta, A, Bm, Cm, Dv, z, out);
}

// Round 6
// 28.142 us; speedup vs baseline: 3.7662x; 1.8375x over previous
//
#include <hip/hip_runtime.h>
#include <math.h>

namespace {

constexpr int kD = 1024;
constexpr int kL = 1024;
constexpr int kN = 16;
constexpr int kE = 8;    // l-steps per thread
constexpr int kJ = 8;    // n-states per thread
constexpr int kT = 256;  // threads per block; block = one (b,d)

__global__ __launch_bounds__(kT)
void selscan(const float* __restrict__ u,
             const float* __restrict__ delta,
             const float* __restrict__ A,
             const float* __restrict__ Bm,
             const float* __restrict__ Cm,
             const float* __restrict__ Dv,
             const float* __restrict__ z,
             float* __restrict__ out)
{
    // wave carry summaries: [wave][nh][j]
    __shared__ float sw_a[4][2][kJ];
    __shared__ float sw_x[4][2][kJ];

    const int bd   = blockIdx.x;
    const int b    = bd >> 10;          // kD = 1024
    const int d    = bd & (kD - 1);
    const int t    = threadIdx.x;
    const int lane = t & 63;
    const int wave = t >> 6;
    const int nh   = t & 1;             // which half of n
    const int n0   = nh << 3;
    const int l0   = (t >> 1) << 3;     // chunk = t>>1, 8 elements each
    const size_t base = (size_t)bd * kL;

    const float LOG2E = 1.4426950408889634f;
    const float LN2   = 0.6931471805599453f;

    // ---- dt = softplus(delta), dtu = dt*u (exp2/log2 forms) ----
    float dt[kE], dtu[kE];
    {
        float4 d0 = *(const float4*)(delta + base + l0);
        float4 d1 = *(const float4*)(delta + base + l0 + 4);
        float4 u0 = *(const float4*)(u + base + l0);
        float4 u1 = *(const float4*)(u + base + l0 + 4);
        float dd[kE] = {d0.x,d0.y,d0.z,d0.w,d1.x,d1.y,d1.z,d1.w};
        float uu[kE] = {u0.x,u0.y,u0.z,u0.w,u1.x,u1.y,u1.z,u1.w};
        #pragma unroll
        for (int s = 0; s < kE; ++s) {
            float x = dd[s];
            float e = __builtin_amdgcn_exp2f(-fabsf(x) * LOG2E);
            float sp = fmaxf(x, 0.f) + __builtin_amdgcn_logf(1.f + e) * LN2;
            dt[s]  = sp;
            dtu[s] = sp * uu[s];
        }
    }

    // ---- A row, pre-scaled by log2(e) for exp2 ----
    float cj[kJ];
    {
        float4 a0 = *(const float4*)(A + d * kN + n0);
        float4 a1 = *(const float4*)(A + d * kN + n0 + 4);
        cj[0]=a0.x*LOG2E; cj[1]=a0.y*LOG2E; cj[2]=a0.z*LOG2E; cj[3]=a0.w*LOG2E;
        cj[4]=a1.x*LOG2E; cj[5]=a1.y*LOG2E; cj[6]=a1.z*LOG2E; cj[7]=a1.w*LOG2E;
    }

    // ---- Phase 1: local scan; accumulate y_local and Q = P*C ----
    float Q[kJ][kE];
    float y[kE] = {0.f,0.f,0.f,0.f,0.f,0.f,0.f,0.f};
    float a_s[kJ], x_s[kJ];
    const int rowbase = (b << 4) + n0;
    #pragma unroll
    for (int j = 0; j < kJ; ++j) {
        const float* Bp = Bm + (size_t)(rowbase + j) * kL + l0;
        const float* Cp = Cm + (size_t)(rowbase + j) * kL + l0;
        float4 b0 = *(const float4*)Bp;
        float4 b1 = *(const float4*)(Bp + 4);
        float4 c0 = *(const float4*)Cp;
        float4 c1 = *(const float4*)(Cp + 4);
        float Bv[kE] = {b0.x,b0.y,b0.z,b0.w,b1.x,b1.y,b1.z,b1.w};
        float Cv[kE] = {c0.x,c0.y,c0.z,c0.w,c1.x,c1.y,c1.z,c1.w};
        float x = 0.f, p = 1.f;
        #pragma unroll
        for (int s = 0; s < kE; ++s) {
            float e = __builtin_amdgcn_exp2f(dt[s] * cj[j]);
            x = fmaf(e, x, dtu[s] * Bv[s]);
            p *= e;
            Q[j][s] = p * Cv[s];
            y[s] = fmaf(x, Cv[s], y[s]);
        }
        a_s[j] = p;
        x_s[j] = x;
    }

    // ---- Cross-chunk carry: Hillis-Steele inclusive scan over lanes (stride 2) ----
    #pragma unroll
    for (int dlt = 2; dlt <= 32; dlt <<= 1) {
        #pragma unroll
        for (int j = 0; j < kJ; ++j) {
            float ain = __shfl_up(a_s[j], dlt, 64);
            float xin = __shfl_up(x_s[j], dlt, 64);
            bool act = (lane >= dlt);
            x_s[j] = fmaf(a_s[j], act ? xin : 0.f, x_s[j]);
            a_s[j] *= act ? ain : 1.f;
        }
    }

    // wave summaries (lanes 62/63 hold the wave-inclusive totals for nh=0/1)
    if (lane >= 62) {
        #pragma unroll
        for (int j = 0; j < kJ; ++j) {
            sw_a[wave][lane & 1][j] = a_s[j];
            sw_x[wave][lane & 1][j] = x_s[j];
        }
    }
    __syncthreads();

    // in-wave exclusive prefix (shift by one chunk = 2 lanes)
    float ea[kJ], ex[kJ];
    #pragma unroll
    for (int j = 0; j < kJ; ++j) {
        float av = __shfl_up(a_s[j], 2, 64);
        float xv = __shfl_up(x_s[j], 2, 64);
        ea[j] = (lane >= 2) ? av : 1.f;
        ex[j] = (lane >= 2) ? xv : 0.f;
    }

    // prefix over preceding waves (<=3 serial fma per j)
    float wx[kJ];
    #pragma unroll
    for (int j = 0; j < kJ; ++j) wx[j] = 0.f;
    #pragma unroll
    for (int w = 0; w < 4; ++w) {
        if (w < wave) {
            #pragma unroll
            for (int j = 0; j < kJ; ++j)
                wx[j] = fmaf(sw_a[w][nh][j], wx[j], sw_x[w][nh][j]);
        }
    }

    // carry into this thread's chunk
    float carry[kJ];
    #pragma unroll
    for (int j = 0; j < kJ; ++j) carry[j] = fmaf(ea[j], wx[j], ex[j]);

    // ---- Phase 2: y += carry_j * Q_j (no loads) ----
    #pragma unroll
    for (int j = 0; j < kJ; ++j)
        #pragma unroll
        for (int s = 0; s < kE; ++s)
            y[s] = fmaf(carry[j], Q[j][s], y[s]);

    // ---- Combine the two n-halves (lane pairs) ----
    #pragma unroll
    for (int s = 0; s < kE; ++s) y[s] += __shfl_xor(y[s], 1, 64);

    // ---- Epilogue: each thread of the pair writes 4 of the 8 elements ----
    const float D_d = Dv[d];
    float y0, y1, y2, y3;
    if (nh == 0) { y0 = y[0]; y1 = y[1]; y2 = y[2]; y3 = y[3]; }
    else         { y0 = y[4]; y1 = y[5]; y2 = y[6]; y3 = y[7]; }

    const int eoff = l0 + nh * 4;   // == 4*t, coalesced
    float4 zv = *(const float4*)(z + base + eoff);
    float4 uv = *(const float4*)(u + base + eoff);
    float s0 = __builtin_amdgcn_rcpf(1.f + __builtin_amdgcn_exp2f(-zv.x * LOG2E));
    float s1 = __builtin_amdgcn_rcpf(1.f + __builtin_amdgcn_exp2f(-zv.y * LOG2E));
    float s2 = __builtin_amdgcn_rcpf(1.f + __builtin_amdgcn_exp2f(-zv.z * LOG2E));
    float s3 = __builtin_amdgcn_rcpf(1.f + __builtin_amdgcn_exp2f(-zv.w * LOG2E));
    float4 o;
    o.x = (y0 + uv.x * D_d) * zv.x * s0;
    o.y = (y1 + uv.y * D_d) * zv.y * s1;
    o.z = (y2 + uv.z * D_d) * zv.z * s2;
    o.w = (y3 + uv.w * D_d) * zv.w * s3;
    *(float4*)(out + base + eoff) = o;
}

}  // namespace

extern "C" void kernel_launch(void* const* d_in, const int* in_sizes, int n_in,
                              void* d_out, int out_size, void* d_ws, size_t ws_size,
                              hipStream_t stream) {
    const float* u     = (const float*)d_in[0];
    const float* delta = (const float*)d_in[1];
    const float* A     = (const float*)d_in[2];
    const float* Bm    = (const float*)d_in[3];
    const float* Cm    = (const float*)d_in[4];
    const float* Dv    = (const float*)d_in[5];
    const float* z     = (const float*)d_in[6];
    float* out = (float*)d_out;

    dim3 grid(2 * kD);
    dim3 block(kT);
    hipLaunchKernelGGL(selscan, grid, block, 0, stream,
                       u, delta, A, Bm, Cm, Dv, z, out);
}

// Round 7
// 26.039 us; speedup vs baseline: 4.0704x; 1.0808x over previous
//
#include <hip/hip_runtime.h>
#include <math.h>

namespace {

constexpr int kD = 1024;
constexpr int kL = 1024;
constexpr int kN = 16;
constexpr int kE = 8;    // l-steps per thread
constexpr int kJ = 8;    // n-states per thread
constexpr int kT = 256;  // threads per block; block = one (b,d)

__global__ __launch_bounds__(kT)
void selscan(const float* __restrict__ u,
             const float* __restrict__ delta,
             const float* __restrict__ A,
             const float* __restrict__ Bm,
             const float* __restrict__ Cm,
             const float* __restrict__ Dv,
             const float* __restrict__ z,
             float* __restrict__ out)
{
    // chunk summaries (a,x) per [chunk][n]; +1 float2 pad per row to stagger banks.
    // After the scanner pass, .x of each slot holds the exclusive carry.
    __shared__ float2 sax[128][kN + 1];   // 128*17*8 = 17408 B

    const int bd   = blockIdx.x;
    const int b    = bd >> 10;          // kD = 1024
    const int d    = bd & (kD - 1);
    const int t    = threadIdx.x;
    const int lane = t & 63;
    const int wave = t >> 6;
    const int nh   = t & 1;             // which half of n
    const int n0   = nh << 3;
    const int chunk = t >> 1;           // 0..127
    const int l0   = chunk << 3;        // 8 elements per chunk
    const size_t base = (size_t)bd * kL;

    const float LOG2E = 1.4426950408889634f;
    const float LN2   = 0.6931471805599453f;

    // ---- dt = softplus(delta), dtu = dt*u (exp2/log2 forms) ----
    float dt[kE], dtu[kE];
    {
        float4 d0 = *(const float4*)(delta + base + l0);
        float4 d1 = *(const float4*)(delta + base + l0 + 4);
        float4 u0 = *(const float4*)(u + base + l0);
        float4 u1 = *(const float4*)(u + base + l0 + 4);
        float dd[kE] = {d0.x,d0.y,d0.z,d0.w,d1.x,d1.y,d1.z,d1.w};
        float uu[kE] = {u0.x,u0.y,u0.z,u0.w,u1.x,u1.y,u1.z,u1.w};
        #pragma unroll
        for (int s = 0; s < kE; ++s) {
            float x = dd[s];
            float e = __builtin_amdgcn_exp2f(-fabsf(x) * LOG2E);
            float sp = fmaxf(x, 0.f) + __builtin_amdgcn_logf(1.f + e) * LN2;
            dt[s]  = sp;
            dtu[s] = sp * uu[s];
        }
    }

    // ---- A row, pre-scaled by log2(e) for exp2 ----
    float cj[kJ];
    {
        float4 a0 = *(const float4*)(A + d * kN + n0);
        float4 a1 = *(const float4*)(A + d * kN + n0 + 4);
        cj[0]=a0.x*LOG2E; cj[1]=a0.y*LOG2E; cj[2]=a0.z*LOG2E; cj[3]=a0.w*LOG2E;
        cj[4]=a1.x*LOG2E; cj[5]=a1.y*LOG2E; cj[6]=a1.z*LOG2E; cj[7]=a1.w*LOG2E;
    }

    // ---- Phase 1: local scan; accumulate y_local and Q = P*C ----
    float Q[kJ][kE];
    float y[kE] = {0.f,0.f,0.f,0.f,0.f,0.f,0.f,0.f};
    const int rowbase = (b << 4) + n0;
    #pragma unroll
    for (int j = 0; j < kJ; ++j) {
        const float* Bp = Bm + (size_t)(rowbase + j) * kL + l0;
        const float* Cp = Cm + (size_t)(rowbase + j) * kL + l0;
        float4 b0 = *(const float4*)Bp;
        float4 b1 = *(const float4*)(Bp + 4);
        float4 c0 = *(const float4*)Cp;
        float4 c1 = *(const float4*)(Cp + 4);
        float Bv[kE] = {b0.x,b0.y,b0.z,b0.w,b1.x,b1.y,b1.z,b1.w};
        float Cv[kE] = {c0.x,c0.y,c0.z,c0.w,c1.x,c1.y,c1.z,c1.w};
        float x = 0.f, p = 1.f;
        #pragma unroll
        for (int s = 0; s < kE; ++s) {
            float e = __builtin_amdgcn_exp2f(dt[s] * cj[j]);
            x = fmaf(e, x, dtu[s] * Bv[s]);
            p *= e;
            Q[j][s] = p * Cv[s];
            y[s] = fmaf(x, Cv[s], y[s]);
        }
        // chunk summary for state n0+j
        sax[chunk][n0 + j] = make_float2(p, x);
    }
    __syncthreads();

    // ---- Scanner: wave 0 computes exclusive carries for all 128 chunks ----
    if (wave == 0) {
        const int sn = lane & 15;       // state n
        const int q  = lane >> 4;       // chunk group (32 chunks each)
        const int cb = q << 5;
        // pass 1: group summary (product of a, local scan of x)
        float p = 1.f, c = 0.f;
        #pragma unroll 8
        for (int i = 0; i < 32; ++i) {
            float2 ax = sax[cb + i][sn];
            c = fmaf(ax.x, c, ax.y);
            p *= ax.x;
        }
        // inclusive scan over the 4 groups (strides 16, 32 in lane space)
        float Ag = p, Xg = c;
        {
            float ain = __shfl_up(Ag, 16, 64);
            float xin = __shfl_up(Xg, 16, 64);
            bool act = (lane >= 16);
            Xg = fmaf(Ag, act ? xin : 0.f, Xg);
            Ag *= act ? ain : 1.f;
            ain = __shfl_up(Ag, 32, 64);
            xin = __shfl_up(Xg, 32, 64);
            act = (lane >= 32);
            Xg = fmaf(Ag, act ? xin : 0.f, Xg);
            Ag *= act ? ain : 1.f;
        }
        // exclusive carry into this group
        float gx = __shfl_up(Xg, 16, 64);
        float cc = (lane >= 16) ? gx : 0.f;
        // pass 2: write per-chunk exclusive carry into the .x slot
        #pragma unroll 8
        for (int i = 0; i < 32; ++i) {
            float2 ax = sax[cb + i][sn];
            sax[cb + i][sn].x = cc;
            cc = fmaf(ax.x, cc, ax.y);
        }
    }
    __syncthreads();

    // ---- Phase 2: y += carry_j * Q_j (carries straight from LDS) ----
    #pragma unroll
    for (int j = 0; j < kJ; ++j) {
        float carry = sax[chunk][n0 + j].x;
        #pragma unroll
        for (int s = 0; s < kE; ++s)
            y[s] = fmaf(carry, Q[j][s], y[s]);
    }

    // ---- Combine the two n-halves (lane pairs) ----
    #pragma unroll
    for (int s = 0; s < kE; ++s) y[s] += __shfl_xor(y[s], 1, 64);

    // ---- Epilogue: each thread of the pair writes 4 of the 8 elements ----
    const float D_d = Dv[d];
    float y0, y1, y2, y3;
    if (nh == 0) { y0 = y[0]; y1 = y[1]; y2 = y[2]; y3 = y[3]; }
    else         { y0 = y[4]; y1 = y[5]; y2 = y[6]; y3 = y[7]; }

    const int eoff = l0 + nh * 4;   // == 4*t, coalesced
    float4 zv = *(const float4*)(z + base + eoff);
    float4 uv = *(const float4*)(u + base + eoff);
    float s0 = __builtin_amdgcn_rcpf(1.f + __builtin_amdgcn_exp2f(-zv.x * LOG2E));
    float s1 = __builtin_amdgcn_rcpf(1.f + __builtin_amdgcn_exp2f(-zv.y * LOG2E));
    float s2 = __builtin_amdgcn_rcpf(1.f + __builtin_amdgcn_exp2f(-zv.z * LOG2E));
    float s3 = __builtin_amdgcn_rcpf(1.f + __builtin_amdgcn_exp2f(-zv.w * LOG2E));
    float4 o;
    o.x = (y0 + uv.x * D_d) * zv.x * s0;
    o.y = (y1 + uv.y * D_d) * zv.y * s1;
    o.z = (y2 + uv.z * D_d) * zv.z * s2;
    o.w = (y3 + uv.w * D_d) * zv.w * s3;
    *(float4*)(out + base + eoff) = o;
}

}  // namespace

extern "C" void kernel_launch(void* const* d_in, const int* in_sizes, int n_in,
                              void* d_out, int out_size, void* d_ws, size_t ws_size,
                              hipStream_t stream) {
    const float* u     = (const float*)d_in[0];
    const float* delta = (const float*)d_in[1];
    const float* A     = (const float*)d_in[2];
    const float* Bm    = (const float*)d_in[3];
    const float* Cm    = (const float*)d_in[4];
    const float* Dv    = (const float*)d_in[5];
    const float* z     = (const float*)d_in[6];
    float* out = (float*)d_out;

    dim3 grid(2 * kD);
    dim3 block(kT);
    hipLaunchKernelGGL(selscan, grid, block, 0, stream,
                       u, delta, A, Bm, Cm, Dv, z, out);
}